// Round 3
// baseline (496.483 us; speedup 1.0000x reference)
//
#include <hip/hip_runtime.h>
#include <hip/hip_bf16.h>
#include <cstdint>

#define BB 64
#define TN 2048
#define RNN 1024
#define EMB 512
#define ATT 128
#define NF 32
#define KS 31
#define PADK 15
#define CKN 62   // 2*KS
#define TT 256   // t-tile for energies kernel

__device__ __forceinline__ float fast_rcp(float x) {
#if __has_builtin(__builtin_amdgcn_rcpf)
    return __builtin_amdgcn_rcpf(x);
#else
    return 1.0f / x;
#endif
}

// tanh(x) = 1 - 2/(exp(2x)+1); saturates correctly for |x| large.
__device__ __forceinline__ float fast_tanh(float x) {
    float s = __expf(2.0f * x);
    return 1.0f - 2.0f * fast_rcp(s + 1.0f);
}

// blocks 0..BB-1: pq[b][a] = dot(hidden[b], Wq[a])   (a = 0..127)
// block BB:       U[a][ck] = sum_f Wd[a][f] * conv_w[f][ck]
__global__ __launch_bounds__(256) void prep_kernel(
    const float* __restrict__ ahs, const float* __restrict__ Wq,
    const float* __restrict__ conv_w, const float* __restrict__ Wd,
    float* __restrict__ ws_pq, float* __restrict__ ws_U)
{
    int tid = threadIdx.x;
    if (blockIdx.x < BB) {
        int b = blockIdx.x;
        __shared__ float sh[RNN];
        for (int i = tid; i < RNN; i += 256) sh[i] = ahs[b * RNN + i];
        __syncthreads();
        int a = tid & 127, half = tid >> 7;  // each (a) split over 2 threads
        const float4* wq4 = (const float4*)(Wq + a * RNN + half * (RNN / 2));
        const float4* sh4 = (const float4*)(sh + half * (RNN / 2));
        float acc = 0.0f;
#pragma unroll 8
        for (int i = 0; i < RNN / 8; ++i) {
            float4 w4 = wq4[i]; float4 h4 = sh4[i];
            acc = fmaf(w4.x, h4.x, acc);
            acc = fmaf(w4.y, h4.y, acc);
            acc = fmaf(w4.z, h4.z, acc);
            acc = fmaf(w4.w, h4.w, acc);
        }
        __shared__ float part[256];
        part[tid] = acc;
        __syncthreads();
        if (half == 0) ws_pq[b * ATT + a] = part[a] + part[a + 128];
    } else {
        __shared__ float sWd[ATT * NF];
        __shared__ float sCw[NF * CKN];
        for (int i = tid; i < ATT * NF; i += 256) sWd[i] = Wd[i];
        for (int i = tid; i < NF * CKN; i += 256) sCw[i] = conv_w[i];
        __syncthreads();
        for (int idx = tid; idx < ATT * CKN; idx += 256) {
            int a = idx / CKN, ck = idx % CKN;
            float acc = 0.0f;
#pragma unroll
            for (int f = 0; f < NF; ++f) acc = fmaf(sWd[a * NF + f], sCw[f * CKN + ck], acc);
            ws_U[idx] = acc;
        }
    }
}

// grid (BB, TN/TT), block 256 (4 waves). Wave handles one t per iter;
// lane l covers a = l and a = l+64. e[b][t] = sum_a v[a]*tanh(pq+lo+pm).
__global__ __launch_bounds__(256) void energies_kernel(
    const float* __restrict__ awc, const float* __restrict__ pm,
    const float* __restrict__ vvec,
    const float* __restrict__ ws_pq, const float* __restrict__ ws_U,
    float* __restrict__ ws_e)
{
    __shared__ float sU[ATT * 63];      // stride 63 -> 2-way LDS aliasing (free)
    __shared__ float sA[2][TT + 32];    // awc tile with 15-halo each side
    __shared__ float sPq[ATT];
    int tid = threadIdx.x;
    int b = blockIdx.x, t0 = blockIdx.y * TT;

    for (int idx = tid; idx < ATT * CKN; idx += 256) {
        int a = idx / CKN, ck = idx % CKN;
        sU[a * 63 + ck] = ws_U[idx];
    }
    for (int idx = tid; idx < 2 * (TT + 30); idx += 256) {
        int c = idx / (TT + 30), tt = idx % (TT + 30);
        int t = t0 + tt - PADK;
        sA[c][tt] = (t >= 0 && t < TN) ? awc[(b * 2 + c) * TN + t] : 0.0f;
    }
    if (tid < ATT) sPq[tid] = ws_pq[b * ATT + tid];
    __syncthreads();

    int lane = tid & 63, wv = tid >> 6;
    float v0 = vvec[lane], v1 = vvec[lane + 64];
    float q0 = sPq[lane], q1 = sPq[lane + 64];
    const float* U0 = &sU[lane * 63];
    const float* U1 = &sU[(lane + 64) * 63];
    const float* pmb = pm + (size_t)b * TN * ATT;

    for (int i = 0; i < TT / 4; ++i) {
        int tl = i * 4 + wv;
        int t = t0 + tl;
        float lo0 = 0.0f, lo1 = 0.0f;
#pragma unroll
        for (int c = 0; c < 2; ++c) {
#pragma unroll
            for (int k = 0; k < KS; ++k) {
                float x = sA[c][tl + k];
                lo0 = fmaf(U0[c * KS + k], x, lo0);
                lo1 = fmaf(U1[c * KS + k], x, lo1);
            }
        }
        float p0 = pmb[(size_t)t * ATT + lane];
        float p1 = pmb[(size_t)t * ATT + 64 + lane];
        float e = v0 * fast_tanh(q0 + lo0 + p0) + v1 * fast_tanh(q1 + lo1 + p1);
#pragma unroll
        for (int off = 32; off >= 1; off >>= 1) e += __shfl_xor(e, off, 64);
        if (lane == 0) ws_e[b * TN + t] = e;
    }
}

// grid BB, block 256: masked softmax over T, weights -> d_out weights region.
__global__ __launch_bounds__(256) void softmax_kernel(
    const float* __restrict__ ws_e, const uint8_t* __restrict__ mask,
    float* __restrict__ out_w)
{
    int b = blockIdx.x, tid = threadIdx.x;
    float vals[TN / 256];
    float m = -INFINITY;
#pragma unroll
    for (int i = 0; i < TN / 256; ++i) {
        int t = tid + i * 256;
        float e = ws_e[b * TN + t];
        if (mask[b * TN + t]) e = -INFINITY;
        vals[i] = e;
        m = fmaxf(m, e);
    }
    __shared__ float redm[4];
#pragma unroll
    for (int off = 32; off >= 1; off >>= 1) m = fmaxf(m, __shfl_xor(m, off, 64));
    if ((tid & 63) == 0) redm[tid >> 6] = m;
    __syncthreads();
    m = fmaxf(fmaxf(redm[0], redm[1]), fmaxf(redm[2], redm[3]));

    float s = 0.0f;
#pragma unroll
    for (int i = 0; i < TN / 256; ++i) s += __expf(vals[i] - m);
    __shared__ float reds[4];
#pragma unroll
    for (int off = 32; off >= 1; off >>= 1) s += __shfl_xor(s, off, 64);
    if ((tid & 63) == 0) reds[tid >> 6] = s;
    __syncthreads();
    s = reds[0] + reds[1] + reds[2] + reds[3];
    float inv = 1.0f / s;
#pragma unroll
    for (int i = 0; i < TN / 256; ++i) {
        int t = tid + i * 256;
        out_w[b * TN + t] = __expf(vals[i] - m) * inv;
    }
}

// grid (BB, nchunk), block 256. Partial context over a t-chunk, float4 e-lanes.
__global__ __launch_bounds__(256) void context_partial_kernel(
    const float* __restrict__ mem, const float* __restrict__ w,
    float* __restrict__ partial, int chunkT)
{
    int b = blockIdx.x, ch = blockIdx.y;
    int tid = threadIdx.x;
    int tc0 = ch * chunkT;
    extern __shared__ float sw[];  // chunkT floats
    for (int i = tid; i < chunkT; i += 256) sw[i] = w[b * TN + tc0 + i];
    __syncthreads();

    int e4 = tid & 127, sub = tid >> 7;
    const float4* m4 = (const float4*)(mem + ((size_t)(b * TN + tc0)) * EMB);
    float4 acc = make_float4(0.f, 0.f, 0.f, 0.f);
    for (int i = sub; i < chunkT; i += 2) {
        float wt = sw[i];
        float4 mv = m4[(size_t)i * 128 + e4];
        acc.x = fmaf(wt, mv.x, acc.x);
        acc.y = fmaf(wt, mv.y, acc.y);
        acc.z = fmaf(wt, mv.z, acc.z);
        acc.w = fmaf(wt, mv.w, acc.w);
    }
    __shared__ float4 sacc[128];
    if (sub == 1) sacc[e4] = acc;
    __syncthreads();
    if (sub == 0) {
        float4 o = sacc[e4];
        acc.x += o.x; acc.y += o.y; acc.z += o.z; acc.w += o.w;
        ((float4*)partial)[((size_t)ch * BB + b) * 128 + e4] = acc;
    }
}

// grid (BB*EMB/256), block 256: sum nchunk partials -> context out.
__global__ __launch_bounds__(256) void context_reduce_kernel(
    const float* __restrict__ partial, float* __restrict__ out_ctx, int nchunk)
{
    int o = blockIdx.x * 256 + threadIdx.x;
    int b = o >> 9, e = o & 511;
    float acc = 0.0f;
    for (int c = 0; c < nchunk; ++c)
        acc += partial[((size_t)c * BB + b) * EMB + e];
    out_ctx[o] = acc;
}

extern "C" void kernel_launch(void* const* d_in, const int* in_sizes, int n_in,
                              void* d_out, int out_size, void* d_ws, size_t ws_size,
                              hipStream_t stream) {
    const float*   ahs  = (const float*)d_in[0];
    const float*   mem  = (const float*)d_in[1];
    const float*   pm   = (const float*)d_in[2];
    const float*   awc  = (const float*)d_in[3];
    const uint8_t* mask = (const uint8_t*)d_in[4];
    const float*   Wq   = (const float*)d_in[5];
    const float*   cw   = (const float*)d_in[6];
    const float*   Wd   = (const float*)d_in[7];
    const float*   v    = (const float*)d_in[8];

    float* out_ctx = (float*)d_out;             // B*EMB
    float* out_w   = (float*)d_out + BB * EMB;  // B*T

    float* ws      = (float*)d_ws;
    float* ws_pq   = ws;            // 8192
    float* ws_U    = ws + 8192;     // 7936
    float* ws_e    = ws + 16384;    // 131072
    float* ws_part = ws + 147456;   // nchunk*BB*EMB

    int nchunk = 16;
    while (nchunk > 1 &&
           (size_t)(147456 + (size_t)nchunk * BB * EMB) * 4 > ws_size)
        nchunk >>= 1;
    int chunkT = TN / nchunk;

    prep_kernel<<<BB + 1, 256, 0, stream>>>(ahs, Wq, cw, Wd, ws_pq, ws_U);
    energies_kernel<<<dim3(BB, TN / TT), 256, 0, stream>>>(awc, pm, v, ws_pq, ws_U, ws_e);
    softmax_kernel<<<BB, 256, 0, stream>>>(ws_e, mask, out_w);
    context_partial_kernel<<<dim3(BB, nchunk), 256, chunkT * 4, stream>>>(mem, out_w, ws_part, chunkT);
    context_reduce_kernel<<<(BB * EMB) / 256, 256, 0, stream>>>(ws_part, out_ctx, nchunk);
}

// Round 4
// 476.985 us; speedup vs baseline: 1.0409x; 1.0409x over previous
//
#include <hip/hip_runtime.h>
#include <hip/hip_bf16.h>
#include <cstdint>

#define BB 64
#define TN 2048
#define RNN 1024
#define EMB 512
#define ATT 128
#define NF 32
#define KS 31
#define PADK 15
#define CKN 62    // 2*KS
#define ETT 256   // t-tile for energies kernel
#define NCHUNK 16
#define CHT 128   // TN / NCHUNK

__device__ __forceinline__ float fast_rcp(float x) {
#if __has_builtin(__builtin_amdgcn_rcpf)
    return __builtin_amdgcn_rcpf(x);
#else
    return 1.0f / x;
#endif
}

// tanh(x) = 1 - 2/(exp(2x)+1); saturates correctly for |x| large.
__device__ __forceinline__ float fast_tanh(float x) {
    float s = __expf(2.0f * x);
    return 1.0f - 2.0f * fast_rcp(s + 1.0f);
}

// blocks 0..BB-1: pq[b][a] = dot(hidden[b], Wq[a])   (a = 0..127)
// block BB:       UT[ck][a] = sum_f Wd[a][f] * conv_w[f][ck]   (transposed!)
__global__ __launch_bounds__(256) void prep_kernel(
    const float* __restrict__ ahs, const float* __restrict__ Wq,
    const float* __restrict__ conv_w, const float* __restrict__ Wd,
    float* __restrict__ ws_pq, float* __restrict__ ws_UT)
{
    int tid = threadIdx.x;
    if (blockIdx.x < BB) {
        int b = blockIdx.x;
        __shared__ float sh[RNN];
        for (int i = tid; i < RNN; i += 256) sh[i] = ahs[b * RNN + i];
        __syncthreads();
        int a = tid & 127, half = tid >> 7;  // each (a) split over 2 threads
        const float4* wq4 = (const float4*)(Wq + a * RNN + half * (RNN / 2));
        const float4* sh4 = (const float4*)(sh + half * (RNN / 2));
        float acc = 0.0f;
#pragma unroll 8
        for (int i = 0; i < RNN / 8; ++i) {
            float4 w4 = wq4[i]; float4 h4 = sh4[i];
            acc = fmaf(w4.x, h4.x, acc);
            acc = fmaf(w4.y, h4.y, acc);
            acc = fmaf(w4.z, h4.z, acc);
            acc = fmaf(w4.w, h4.w, acc);
        }
        __shared__ float part[256];
        part[tid] = acc;
        __syncthreads();
        if (half == 0) ws_pq[b * ATT + a] = part[a] + part[a + 128];
    } else {
        __shared__ float sWd[ATT * NF];
        __shared__ float sCw[NF * CKN];
        for (int i = tid; i < ATT * NF; i += 256) sWd[i] = Wd[i];
        for (int i = tid; i < NF * CKN; i += 256) sCw[i] = conv_w[i];
        __syncthreads();
        // idx = ck*128 + a  -> coalesced writes of the transposed U
        for (int idx = tid; idx < ATT * CKN; idx += 256) {
            int a = idx & 127, ck = idx >> 7;
            float acc = 0.0f;
#pragma unroll
            for (int f = 0; f < NF; ++f) acc = fmaf(sWd[a * NF + f], sCw[f * CKN + ck], acc);
            ws_UT[idx] = acc;
        }
    }
}

// grid (BB, TN/ETT), block 256 = 4 waves.
// wave w: a-half h = w&1 (lane -> a = h*64+lane), t-segment seg = w>>1.
// U[a][0..61] lives in 62 VGPRs (loaded once). Conv window from LDS tile,
// 34 broadcast reads serve 4 unrolled t's. Halves combine through LDS.
__global__ __launch_bounds__(256) void energies_kernel(
    const float* __restrict__ awc, const float* __restrict__ pm,
    const float* __restrict__ vvec,
    const float* __restrict__ ws_pq, const float* __restrict__ ws_UT,
    float* __restrict__ ws_e)
{
    __shared__ float sA[2][ETT + 32];   // awc tile, 15-halo each side
    __shared__ float sE[2][ETT];        // per-half energy partials
    int tid = threadIdx.x;
    int b = blockIdx.x, t0 = blockIdx.y * ETT;

    for (int idx = tid; idx < 2 * (ETT + 30); idx += 256) {
        int c = idx / (ETT + 30), tt = idx % (ETT + 30);
        int t = t0 + tt - PADK;
        sA[c][tt] = (t >= 0 && t < TN) ? awc[(b * 2 + c) * TN + t] : 0.0f;
    }

    int lane = tid & 63, w = tid >> 6;
    int h = w & 1, seg = w >> 1;
    int a = h * 64 + lane;

    float U[CKN];
#pragma unroll
    for (int k = 0; k < CKN; ++k) U[k] = ws_UT[k * ATT + a];   // coalesced
    float q = ws_pq[b * ATT + a];
    float vv = vvec[a];
    const float* pmb = pm + (size_t)b * TN * ATT + a;
    __syncthreads();

    int tbeg = seg * (ETT / 2);
    for (int tl = tbeg; tl < tbeg + ETT / 2; tl += 4) {
        float xw0[34], xw1[34];
#pragma unroll
        for (int j = 0; j < 34; ++j) {
            xw0[j] = sA[0][tl + j];
            xw1[j] = sA[1][tl + j];
        }
        float p[4];
#pragma unroll
        for (int u = 0; u < 4; ++u)
            p[u] = pmb[(size_t)(t0 + tl + u) * ATT];
#pragma unroll
        for (int u = 0; u < 4; ++u) {
            float lo = 0.0f;
#pragma unroll
            for (int k = 0; k < KS; ++k) {
                lo = fmaf(U[k],      xw0[u + k], lo);
                lo = fmaf(U[KS + k], xw1[u + k], lo);
            }
            float e = vv * fast_tanh(q + lo + p[u]);
#pragma unroll
            for (int off = 32; off >= 1; off >>= 1) e += __shfl_xor(e, off, 64);
            if (lane == 0) sE[h][tl + u] = e;
        }
    }
    __syncthreads();
    ws_e[b * TN + t0 + tid] = sE[0][tid] + sE[1][tid];
}

// grid (BB, NCHUNK), block 256. Each block: recompute row softmax stats
// (deterministic, identical across the 16 blocks of a row), write weights
// for its 128-t chunk to out_w, and accumulate its partial context.
__global__ __launch_bounds__(256) void context_fused_kernel(
    const float* __restrict__ ws_e, const uint8_t* __restrict__ mask,
    const float* __restrict__ mem,
    float* __restrict__ out_w, float* __restrict__ partial)
{
    int b = blockIdx.x, ch = blockIdx.y, tid = threadIdx.x;

    // full-row max and sum (8 values per thread)
    float vals[TN / 256];
    float m = -INFINITY;
#pragma unroll
    for (int i = 0; i < TN / 256; ++i) {
        int t = tid + i * 256;
        float e = ws_e[b * TN + t];
        if (mask[b * TN + t]) e = -INFINITY;
        vals[i] = e;
        m = fmaxf(m, e);
    }
    __shared__ float redm[4];
#pragma unroll
    for (int off = 32; off >= 1; off >>= 1) m = fmaxf(m, __shfl_xor(m, off, 64));
    if ((tid & 63) == 0) redm[tid >> 6] = m;
    __syncthreads();
    m = fmaxf(fmaxf(redm[0], redm[1]), fmaxf(redm[2], redm[3]));

    float s = 0.0f;
#pragma unroll
    for (int i = 0; i < TN / 256; ++i) s += __expf(vals[i] - m);
    __shared__ float reds[4];
#pragma unroll
    for (int off = 32; off >= 1; off >>= 1) s += __shfl_xor(s, off, 64);
    if ((tid & 63) == 0) reds[tid >> 6] = s;
    __syncthreads();
    s = reds[0] + reds[1] + reds[2] + reds[3];
    float inv = 1.0f / s;

    // weights for this block's chunk
    __shared__ float sw[CHT];
    int tc0 = ch * CHT;
    if (tid < CHT) {
        int t = tc0 + tid;
        float e = ws_e[b * TN + t];
        if (mask[b * TN + t]) e = -INFINITY;
        float wgt = __expf(e - m) * inv;
        out_w[b * TN + t] = wgt;
        sw[tid] = wgt;
    }
    __syncthreads();

    // weighted sum over chunk rows, float4 lanes
    int e4 = tid & 127, sub = tid >> 7;
    const float4* m4 = (const float4*)(mem + ((size_t)(b * TN + tc0)) * EMB);
    float4 acc = make_float4(0.f, 0.f, 0.f, 0.f);
    for (int i = sub; i < CHT; i += 2) {
        float wt = sw[i];
        float4 mv = m4[(size_t)i * 128 + e4];
        acc.x = fmaf(wt, mv.x, acc.x);
        acc.y = fmaf(wt, mv.y, acc.y);
        acc.z = fmaf(wt, mv.z, acc.z);
        acc.w = fmaf(wt, mv.w, acc.w);
    }
    __shared__ float4 sacc[128];
    if (sub == 1) sacc[e4] = acc;
    __syncthreads();
    if (sub == 0) {
        float4 o = sacc[e4];
        acc.x += o.x; acc.y += o.y; acc.z += o.z; acc.w += o.w;
        ((float4*)partial)[((size_t)ch * BB + b) * 128 + e4] = acc;
    }
}

// grid (BB*EMB/256), block 256: sum NCHUNK partials -> context out.
__global__ __launch_bounds__(256) void context_reduce_kernel(
    const float* __restrict__ partial, float* __restrict__ out_ctx)
{
    int o = blockIdx.x * 256 + threadIdx.x;
    int b = o >> 9, e = o & 511;
    float acc = 0.0f;
#pragma unroll
    for (int c = 0; c < NCHUNK; ++c)
        acc += partial[((size_t)c * BB + b) * EMB + e];
    out_ctx[o] = acc;
}

extern "C" void kernel_launch(void* const* d_in, const int* in_sizes, int n_in,
                              void* d_out, int out_size, void* d_ws, size_t ws_size,
                              hipStream_t stream) {
    const float*   ahs  = (const float*)d_in[0];
    const float*   mem  = (const float*)d_in[1];
    const float*   pm   = (const float*)d_in[2];
    const float*   awc  = (const float*)d_in[3];
    const uint8_t* mask = (const uint8_t*)d_in[4];
    const float*   Wq   = (const float*)d_in[5];
    const float*   cw   = (const float*)d_in[6];
    const float*   Wd   = (const float*)d_in[7];
    const float*   v    = (const float*)d_in[8];

    float* out_ctx = (float*)d_out;             // B*EMB
    float* out_w   = (float*)d_out + BB * EMB;  // B*T

    float* ws      = (float*)d_ws;
    float* ws_pq   = ws;            // 8192 floats
    float* ws_UT   = ws + 8192;     // 7936 floats (transposed U: [ck][a])
    float* ws_e    = ws + 16384;    // 131072 floats
    float* ws_part = ws + 147456;   // NCHUNK*BB*EMB floats

    prep_kernel<<<BB + 1, 256, 0, stream>>>(ahs, Wq, cw, Wd, ws_pq, ws_UT);
    energies_kernel<<<dim3(BB, TN / ETT), 256, 0, stream>>>(awc, pm, v, ws_pq, ws_UT, ws_e);
    context_fused_kernel<<<dim3(BB, NCHUNK), 256, 0, stream>>>(ws_e, mask, mem, out_w, ws_part);
    context_reduce_kernel<<<(BB * EMB) / 256, 256, 0, stream>>>(ws_part, out_ctx);
}